// Round 2
// baseline (5390.925 us; speedup 1.0000x reference)
//
#include <hip/hip_runtime.h>
#include <cmath>
#include <stdint.h>

#define NLEV  16
#define TSIZE (1u<<19)
#define PRES  512
#define PFD   8
#define HID   64

struct ResArr { float v[NLEV]; };

__device__ __forceinline__ float4 ld4(const float* p){ return *reinterpret_cast<const float4*>(p); }

// acc[o] += wT_col[o] * v  for o=0..63, static indexing only (keeps acc in VGPRs)
#define AXPY64(A, WPTR, V) do { const float* _w=(WPTR); const float _v=(V); \
  _Pragma("unroll") \
  for (int _o=0;_o<64;_o+=4){ float4 _w4=ld4(_w+_o); \
    A[_o+0]=fmaf(_w4.x,_v,A[_o+0]); A[_o+1]=fmaf(_w4.y,_v,A[_o+1]); \
    A[_o+2]=fmaf(_w4.z,_v,A[_o+2]); A[_o+3]=fmaf(_w4.w,_v,A[_o+3]); } } while(0)

__device__ __forceinline__ void plane_enc(const float* __restrict__ planes,
                                          float p0, float p1, float p2, float* pfv)
{
#pragma unroll
    for (int i=0;i<3;i++){
        float ua = (i==2? p1 : p0)*511.f;
        float va = (i==0? p1 : p2)*511.f;
        float uf=floorf(ua), vf=floorf(va);
        float wu=ua-uf, wv=va-vf;
        int u0=(int)uf; u0 = u0<0?0:(u0>510?510:u0);
        int v0=(int)vf; v0 = v0<0?0:(v0>510?510:v0);
        const float* pl = planes + ((size_t)i*PRES*PRES + (size_t)(u0*PRES+v0))*PFD;
        float4 a0=ld4(pl),              a1=ld4(pl+4);
        float4 b0=ld4(pl+PFD),          b1=ld4(pl+PFD+4);
        float4 c0=ld4(pl+PRES*PFD),     c1=ld4(pl+PRES*PFD+4);
        float4 d0=ld4(pl+PRES*PFD+PFD), d1=ld4(pl+PRES*PFD+PFD+4);
        float w00=(1.f-wu)*(1.f-wv), w01=(1.f-wu)*wv, w10=wu*(1.f-wv), w11=wu*wv;
        pfv[i*8+0]=a0.x*w00+b0.x*w01+c0.x*w10+d0.x*w11;
        pfv[i*8+1]=a0.y*w00+b0.y*w01+c0.y*w10+d0.y*w11;
        pfv[i*8+2]=a0.z*w00+b0.z*w01+c0.z*w10+d0.z*w11;
        pfv[i*8+3]=a0.w*w00+b0.w*w01+c0.w*w10+d0.w*w11;
        pfv[i*8+4]=a1.x*w00+b1.x*w01+c1.x*w10+d1.x*w11;
        pfv[i*8+5]=a1.y*w00+b1.y*w01+c1.y*w10+d1.y*w11;
        pfv[i*8+6]=a1.z*w00+b1.z*w01+c1.z*w10+d1.z*w11;
        pfv[i*8+7]=a1.w*w00+b1.w*w01+c1.w*w10+d1.w*w11;
    }
}

// ===================== K1: hash + plane encode + sigma MLP =====================
// LDS 18.4KB -> 8 blocks/CU -> 32 waves/CU. No spills (peak live ~150 VGPR).
__global__ __launch_bounds__(256, 8)
void nerf_k1(const float* __restrict__ x,
             const float* __restrict__ hash_tables,
             const float* __restrict__ planes,
             const float* __restrict__ w_sigma0,
             const float* __restrict__ w_sigma1,
             float* __restrict__ ws16,
             ResArr res, int npts)
{
    __shared__ float s_ws0T[56*64];   // sigma0: in 56 -> out 64 (transposed)
    __shared__ float s_ws1T[64*16];   // sigma1: in 64 -> out 16 (transposed)

    for (int i = threadIdx.x; i < 56*64;  i += 256){ int k=i>>6, o=i&63; s_ws0T[i] = w_sigma0[o*56+k]; }
    for (int i = threadIdx.x; i < 64*16;  i += 256){ int k=i>>4, j=i&15; s_ws1T[i] = w_sigma1[j*64+k]; }
    __syncthreads();

    int n = blockIdx.x*256 + threadIdx.x;
    if (n >= npts) return;

    const float* xr = x + (size_t)n*7;
    float px=xr[0], py=xr[1], pz=xr[2];
    float p0=(px+1.f)*0.5f, p1=(py+1.f)*0.5f, p2=(pz+1.f)*0.5f;

    float acc[HID];
#pragma unroll
    for (int o=0;o<HID;o++) acc[o]=0.f;

    const float2* tabs = reinterpret_cast<const float2*>(hash_tables);
#pragma unroll 4
    for (int l=0; l<NLEV; l++){
        float R = res.v[l];
        float ax=p0*R, ay=p1*R, az=p2*R;
        float fx=floorf(ax), fy=floorf(ay), fz=floorf(az);
        float rx=ax-fx, ry=ay-fy, rz=az-fz;
        uint32_t ix=(uint32_t)fx, iy=(uint32_t)fy, iz=(uint32_t)fz;
        const float2* tab = tabs + (size_t)l*TSIZE;
        uint32_t hx0=ix,               hx1=ix+1u;
        uint32_t hy0=iy*2654435761u,   hy1=(iy+1u)*2654435761u;
        uint32_t hz0=iz*805459861u,    hz1=(iz+1u)*805459861u;
        float wx0=1.f-rx, wx1=rx, wy0=1.f-ry, wy1=ry, wz0=1.f-rz, wz1=rz;
        float f0=0.f, f1=0.f;
#pragma unroll
        for (int c=0;c<8;c++){
            uint32_t hxx=(c&4)?hx1:hx0;
            uint32_t hyy=(c&2)?hy1:hy0;
            uint32_t hzz=(c&1)?hz1:hz0;
            uint32_t idx=(hxx^hyy^hzz)&(TSIZE-1u);
            float2 t = tab[idx];
            float w = ((c&4)?wx1:wx0)*((c&2)?wy1:wy0)*((c&1)?wz1:wz0);
            f0 = fmaf(w,t.x,f0);
            f1 = fmaf(w,t.y,f1);
        }
        AXPY64(acc, &s_ws0T[(2*l+0)*64], f0);
        AXPY64(acc, &s_ws0T[(2*l+1)*64], f1);
    }

    float pfv[24];
    plane_enc(planes, p0, p1, p2, pfv);
#pragma unroll
    for (int j=0;j<24;j++){
        AXPY64(acc, &s_ws0T[(32+j)*64], pfv[j]);
    }

    // sigma1: 16 outputs from relu(acc)
    float h1[16];
#pragma unroll
    for (int j=0;j<16;j++) h1[j]=0.f;
#pragma unroll
    for (int k=0;k<HID;k++){
        float v = fmaxf(acc[k], 0.f);
        const float* wr = &s_ws1T[k*16];
#pragma unroll
        for (int j=0;j<16;j+=4){
            float4 w=ld4(wr+j);
            h1[j+0]=fmaf(w.x,v,h1[j+0]); h1[j+1]=fmaf(w.y,v,h1[j+1]);
            h1[j+2]=fmaf(w.z,v,h1[j+2]); h1[j+3]=fmaf(w.w,v,h1[j+3]);
        }
    }
    float sg = fminf(fmaxf(h1[0], -15.f), 15.f);
    float sigma = expf(sg);

    // ws layout per point: [geo(15), sigma(1)] -> 4x float4 stores
    float* w = ws16 + (size_t)n*16;
    float4 s0 = make_float4(h1[1],h1[2],h1[3],h1[4]);
    float4 s1 = make_float4(h1[5],h1[6],h1[7],h1[8]);
    float4 s2 = make_float4(h1[9],h1[10],h1[11],h1[12]);
    float4 s3 = make_float4(h1[13],h1[14],h1[15],sigma);
    *reinterpret_cast<float4*>(w+0)  = s0;
    *reinterpret_cast<float4*>(w+4)  = s1;
    *reinterpret_cast<float4*>(w+8)  = s2;
    *reinterpret_cast<float4*>(w+12) = s3;
}

// ===================== K2: SH + color MLP =====================
// LDS 43.8KB, block=512 -> 3 blocks/CU -> 24 waves/CU (75%). Recomputes planes.
__global__ __launch_bounds__(512, 6)
void nerf_k2(const float* __restrict__ x,
             const float* __restrict__ planes,
             const float* __restrict__ embed_a,
             const float* __restrict__ w_color0,
             const float* __restrict__ w_color1,
             const float* __restrict__ w_color2,
             const float* __restrict__ ws16,
             float* __restrict__ out, int npts)
{
    __shared__ float s_wc0T[103*64];  // color0: in 103 -> out 64
    __shared__ float s_wc1T[64*64];   // color1: in 64 -> out 64
    __shared__ float s_wc2T[64*4];    // color2: in 64 -> out 3 (pad 4)

    for (int i = threadIdx.x; i < 103*64; i += 512){ int k=i>>6, o=i&63; s_wc0T[i] = w_color0[o*103+k]; }
    for (int i = threadIdx.x; i < 64*64;  i += 512){ int k=i>>6, o=i&63; s_wc1T[i] = w_color1[o*64+k]; }
    for (int i = threadIdx.x; i < 64*4;   i += 512){ int k=i>>2, o=i&3;  s_wc2T[i] = (o<3)? w_color2[o*64+k] : 0.f; }
    __syncthreads();

    int n = blockIdx.x*512 + threadIdx.x;
    if (n >= npts) return;

    const float* xr = x + (size_t)n*7;
    float px=xr[0], py=xr[1], pz=xr[2];
    float dx=xr[3], dy=xr[4], dz=xr[5];
    float appf = xr[6];
    float p0=(px+1.f)*0.5f, p1=(py+1.f)*0.5f, p2=(pz+1.f)*0.5f;

    float pfv[24];
    plane_enc(planes, p0, p1, p2, pfv);

    float acc[HID];
#pragma unroll
    for (int o=0;o<HID;o++) acc[o]=0.f;

    // SH(16)
    float nrm = sqrtf(dx*dx+dy*dy+dz*dz);
    float sx=dx/nrm, sy=dy/nrm, sz=dz/nrm;
    float xx=sx*sx, yy=sy*sy, zz=sz*sz, xyv=sx*sy, yzv=sy*sz, xzv=sx*sz;
    float sh[16];
    sh[0]=0.28209479177387814f;
    sh[1]=-0.48860251190291987f*sy;
    sh[2]= 0.48860251190291987f*sz;
    sh[3]=-0.48860251190291987f*sx;
    sh[4]= 1.0925484305920792f*xyv;
    sh[5]=-1.0925484305920792f*yzv;
    sh[6]= 0.94617469575756f*zz-0.31539156525252005f;
    sh[7]=-1.0925484305920792f*xzv;
    sh[8]= 0.5462742152960396f*(xx-yy);
    sh[9]=-0.5900435899266435f*sy*(3.f*xx-yy);
    sh[10]=2.890611442640554f*xyv*sz;
    sh[11]=-0.4570457994644658f*sy*(4.f*zz-xx-yy);
    sh[12]=0.3731763325901154f*sz*(2.f*zz-3.f*xx-3.f*yy);
    sh[13]=-0.4570457994644658f*sx*(4.f*zz-xx-yy);
    sh[14]=1.445305721320277f*sz*(xx-yy);
    sh[15]=-0.5900435899266435f*sx*(xx-3.f*yy);
#pragma unroll
    for (int k=0;k<16;k++){
        AXPY64(acc, &s_wc0T[k*64], sh[k]);
    }

    // geo(15) + sigma from workspace
    const float* wsr = ws16 + (size_t)n*16;
    float4 g0=ld4(wsr), g1=ld4(wsr+4), g2=ld4(wsr+8), g3=ld4(wsr+12);
    float geo[15] = {g0.x,g0.y,g0.z,g0.w, g1.x,g1.y,g1.z,g1.w,
                     g2.x,g2.y,g2.z,g2.w, g3.x,g3.y,g3.z};
    float sigma = g3.w;
#pragma unroll
    for (int j=0;j<15;j++){
        AXPY64(acc, &s_wc0T[(16+j)*64], geo[j]);
    }

    // app(48)
    {
        int ai = (int)appf;
        const float* ar = embed_a + (size_t)ai*48;
        for (int q=0;q<12;q++){
            float4 av = ld4(ar + q*4);
            const float* wc = &s_wc0T[(31+q*4)*64];
            AXPY64(acc, wc,       av.x);
            AXPY64(acc, wc+64,    av.y);
            AXPY64(acc, wc+128,   av.z);
            AXPY64(acc, wc+192,   av.w);
        }
    }

    // pf(24)
#pragma unroll
    for (int j=0;j<24;j++){
        AXPY64(acc, &s_wc0T[(79+j)*64], pfv[j]);
    }

    // color1: 64x64
    float acc2[HID];
#pragma unroll
    for (int o=0;o<HID;o++) acc2[o]=0.f;
#pragma unroll
    for (int k=0;k<HID;k++){
        float v = fmaxf(acc[k], 0.f);
        AXPY64(acc2, &s_wc1T[k*64], v);
    }

    // color2 + sigmoid + store
    float c0a=0.f, c1a=0.f, c2a=0.f;
#pragma unroll
    for (int k=0;k<HID;k++){
        float v = fmaxf(acc2[k], 0.f);
        float4 w = ld4(&s_wc2T[k*4]);
        c0a=fmaf(w.x,v,c0a); c1a=fmaf(w.y,v,c1a); c2a=fmaf(w.z,v,c2a);
    }
    float4 o4;
    o4.x = 1.f/(1.f+expf(-c0a));
    o4.y = 1.f/(1.f+expf(-c1a));
    o4.z = 1.f/(1.f+expf(-c2a));
    o4.w = sigma;
    *reinterpret_cast<float4*>(out + (size_t)n*4) = o4;
}

// ===================== fallback single kernel (round-1, used only if ws too small) =====================
__global__ __launch_bounds__(256, 2)
void nerf_fwd(const float* __restrict__ x,
              const float* __restrict__ hash_tables,
              const float* __restrict__ planes,
              const float* __restrict__ embed_a,
              const float* __restrict__ w_sigma0,
              const float* __restrict__ w_sigma1,
              const float* __restrict__ w_color0,
              const float* __restrict__ w_color1,
              const float* __restrict__ w_color2,
              float* __restrict__ out,
              ResArr res, int npts)
{
    __shared__ float s_ws0T[56*64];
    __shared__ float s_ws1T[64*16];
    __shared__ float s_wc0T[103*64];
    __shared__ float s_wc1T[64*64];
    __shared__ float s_wc2T[64*4];

    for (int i = threadIdx.x; i < 56*64;  i += 256){ int k=i>>6, o=i&63; s_ws0T[i] = w_sigma0[o*56+k]; }
    for (int i = threadIdx.x; i < 64*16;  i += 256){ int k=i>>4, j=i&15; s_ws1T[i] = w_sigma1[j*64+k]; }
    for (int i = threadIdx.x; i < 103*64; i += 256){ int k=i>>6, o=i&63; s_wc0T[i] = w_color0[o*103+k]; }
    for (int i = threadIdx.x; i < 64*64;  i += 256){ int k=i>>6, o=i&63; s_wc1T[i] = w_color1[o*64+k]; }
    for (int i = threadIdx.x; i < 64*4;   i += 256){ int k=i>>2, o=i&3;  s_wc2T[i] = (o<3)? w_color2[o*64+k] : 0.f; }
    __syncthreads();

    int n = blockIdx.x*256 + threadIdx.x;
    if (n >= npts) return;

    const float* xr = x + (size_t)n*7;
    float px=xr[0], py=xr[1], pz=xr[2];
    float dx=xr[3], dy=xr[4], dz=xr[5];
    float appf = xr[6];
    float p0=(px+1.f)*0.5f, p1=(py+1.f)*0.5f, p2=(pz+1.f)*0.5f;

    float acc[HID];
#pragma unroll
    for (int o=0;o<HID;o++) acc[o]=0.f;

    const float2* tabs = reinterpret_cast<const float2*>(hash_tables);
    for (int l=0; l<NLEV; l++){
        float R = res.v[l];
        float ax=p0*R, ay=p1*R, az=p2*R;
        float fx=floorf(ax), fy=floorf(ay), fz=floorf(az);
        float rx=ax-fx, ry=ay-fy, rz=az-fz;
        uint32_t ix=(uint32_t)fx, iy=(uint32_t)fy, iz=(uint32_t)fz;
        const float2* tab = tabs + (size_t)l*TSIZE;
        uint32_t hx0=ix,               hx1=ix+1u;
        uint32_t hy0=iy*2654435761u,   hy1=(iy+1u)*2654435761u;
        uint32_t hz0=iz*805459861u,    hz1=(iz+1u)*805459861u;
        float wx0=1.f-rx, wx1=rx, wy0=1.f-ry, wy1=ry, wz0=1.f-rz, wz1=rz;
        float f0=0.f, f1=0.f;
#pragma unroll
        for (int c=0;c<8;c++){
            uint32_t hxx=(c&4)?hx1:hx0;
            uint32_t hyy=(c&2)?hy1:hy0;
            uint32_t hzz=(c&1)?hz1:hz0;
            uint32_t idx=(hxx^hyy^hzz)&(TSIZE-1u);
            float2 t = tab[idx];
            float w = ((c&4)?wx1:wx0)*((c&2)?wy1:wy0)*((c&1)?wz1:wz0);
            f0 = fmaf(w,t.x,f0);
            f1 = fmaf(w,t.y,f1);
        }
        AXPY64(acc, &s_ws0T[(2*l+0)*64], f0);
        AXPY64(acc, &s_ws0T[(2*l+1)*64], f1);
    }

    float pfv[24];
    plane_enc(planes, p0, p1, p2, pfv);
#pragma unroll
    for (int j=0;j<24;j++){
        AXPY64(acc, &s_ws0T[(32+j)*64], pfv[j]);
    }

    float h1[16];
#pragma unroll
    for (int j=0;j<16;j++) h1[j]=0.f;
#pragma unroll
    for (int k=0;k<HID;k++){
        float v = fmaxf(acc[k], 0.f);
        const float* wr = &s_ws1T[k*16];
#pragma unroll
        for (int j=0;j<16;j+=4){
            float4 w=ld4(wr+j);
            h1[j+0]=fmaf(w.x,v,h1[j+0]); h1[j+1]=fmaf(w.y,v,h1[j+1]);
            h1[j+2]=fmaf(w.z,v,h1[j+2]); h1[j+3]=fmaf(w.w,v,h1[j+3]);
        }
    }
    float sg = fminf(fmaxf(h1[0], -15.f), 15.f);
    float sigma = expf(sg);

#pragma unroll
    for (int o=0;o<HID;o++) acc[o]=0.f;

    float nrm = sqrtf(dx*dx+dy*dy+dz*dz);
    float sx=dx/nrm, sy=dy/nrm, sz=dz/nrm;
    float xx=sx*sx, yy=sy*sy, zz=sz*sz, xyv=sx*sy, yzv=sy*sz, xzv=sx*sz;
    float sh[16];
    sh[0]=0.28209479177387814f;
    sh[1]=-0.48860251190291987f*sy;
    sh[2]= 0.48860251190291987f*sz;
    sh[3]=-0.48860251190291987f*sx;
    sh[4]= 1.0925484305920792f*xyv;
    sh[5]=-1.0925484305920792f*yzv;
    sh[6]= 0.94617469575756f*zz-0.31539156525252005f;
    sh[7]=-1.0925484305920792f*xzv;
    sh[8]= 0.5462742152960396f*(xx-yy);
    sh[9]=-0.5900435899266435f*sy*(3.f*xx-yy);
    sh[10]=2.890611442640554f*xyv*sz;
    sh[11]=-0.4570457994644658f*sy*(4.f*zz-xx-yy);
    sh[12]=0.3731763325901154f*sz*(2.f*zz-3.f*xx-3.f*yy);
    sh[13]=-0.4570457994644658f*sx*(4.f*zz-xx-yy);
    sh[14]=1.445305721320277f*sz*(xx-yy);
    sh[15]=-0.5900435899266435f*sx*(xx-3.f*yy);
#pragma unroll
    for (int k=0;k<16;k++){
        AXPY64(acc, &s_wc0T[k*64], sh[k]);
    }
#pragma unroll
    for (int j=0;j<15;j++){
        AXPY64(acc, &s_wc0T[(16+j)*64], h1[1+j]);
    }
    {
        int ai = (int)appf;
        const float* ar = embed_a + (size_t)ai*48;
        for (int q=0;q<12;q++){
            float4 av = ld4(ar + q*4);
            const float* wc = &s_wc0T[(31+q*4)*64];
            AXPY64(acc, wc,       av.x);
            AXPY64(acc, wc+64,    av.y);
            AXPY64(acc, wc+128,   av.z);
            AXPY64(acc, wc+192,   av.w);
        }
    }
#pragma unroll
    for (int j=0;j<24;j++){
        AXPY64(acc, &s_wc0T[(79+j)*64], pfv[j]);
    }

    float acc2[HID];
#pragma unroll
    for (int o=0;o<HID;o++) acc2[o]=0.f;
#pragma unroll
    for (int k=0;k<HID;k++){
        float v = fmaxf(acc[k], 0.f);
        AXPY64(acc2, &s_wc1T[k*64], v);
    }

    float c0a=0.f, c1a=0.f, c2a=0.f;
#pragma unroll
    for (int k=0;k<HID;k++){
        float v = fmaxf(acc2[k], 0.f);
        float4 w = ld4(&s_wc2T[k*4]);
        c0a=fmaf(w.x,v,c0a); c1a=fmaf(w.y,v,c1a); c2a=fmaf(w.z,v,c2a);
    }
    float4 o4;
    o4.x = 1.f/(1.f+expf(-c0a));
    o4.y = 1.f/(1.f+expf(-c1a));
    o4.z = 1.f/(1.f+expf(-c2a));
    o4.w = sigma;
    *reinterpret_cast<float4*>(out + (size_t)n*4) = o4;
}

extern "C" void kernel_launch(void* const* d_in, const int* in_sizes, int n_in,
                              void* d_out, int out_size, void* d_ws, size_t ws_size,
                              hipStream_t stream) {
    const float* x        = (const float*)d_in[0];
    const float* ht       = (const float*)d_in[1];
    const float* planes   = (const float*)d_in[2];
    const float* embed_a  = (const float*)d_in[3];
    const float* w_sigma0 = (const float*)d_in[4];
    const float* w_sigma1 = (const float*)d_in[5];
    const float* w_color0 = (const float*)d_in[6];
    const float* w_color1 = (const float*)d_in[7];
    const float* w_color2 = (const float*)d_in[8];
    float* out = (float*)d_out;

    int npts = in_sizes[0] / 7;

    // Replicate numpy's RES bit-exactly (same libm chain).
    ResArr res;
    double b = exp((log(2048.0) - log(16.0)) / 15.0);
    for (int l=0; l<NLEV; l++)
        res.v[l] = (float)floor(16.0 * pow(b, (double)l));

    size_t ws_needed = (size_t)npts * 16 * sizeof(float);
    if (ws_size >= ws_needed) {
        float* ws16 = (float*)d_ws;
        int g1 = (npts + 255) / 256;
        hipLaunchKernelGGL(nerf_k1, dim3(g1), dim3(256), 0, stream,
                           x, ht, planes, w_sigma0, w_sigma1, ws16, res, npts);
        int g2 = (npts + 511) / 512;
        hipLaunchKernelGGL(nerf_k2, dim3(g2), dim3(512), 0, stream,
                           x, planes, embed_a, w_color0, w_color1, w_color2,
                           ws16, out, npts);
    } else {
        int grid = (npts + 255) / 256;
        hipLaunchKernelGGL(nerf_fwd, dim3(grid), dim3(256), 0, stream,
                           x, ht, planes, embed_a,
                           w_sigma0, w_sigma1, w_color0, w_color1, w_color2,
                           out, res, npts);
    }
}

// Round 3
// 1922.935 us; speedup vs baseline: 2.8035x; 2.8035x over previous
//
#include <hip/hip_runtime.h>
#include <cmath>
#include <stdint.h>

#define NLEV  16
#define TSIZE (1u<<19)
#define PRES  512
#define PFD   8
#define HID   64

struct ResArr { float v[NLEV]; };

__device__ __forceinline__ float4 ld4(const float* p){ return *reinterpret_cast<const float4*>(p); }

// acc[o] += wT_col[o] * v  for o=0..63, static indexing only (keeps acc in VGPRs)
#define AXPY64(A, WPTR, V) do { const float* _w=(WPTR); const float _v=(V); \
  _Pragma("unroll") \
  for (int _o=0;_o<64;_o+=4){ float4 _w4=ld4(_w+_o); \
    A[_o+0]=fmaf(_w4.x,_v,A[_o+0]); A[_o+1]=fmaf(_w4.y,_v,A[_o+1]); \
    A[_o+2]=fmaf(_w4.z,_v,A[_o+2]); A[_o+3]=fmaf(_w4.w,_v,A[_o+3]); } } while(0)

// 32-wide variant for the register-pressure-split color1
#define AXPY32(A, WPTR, V) do { const float* _w=(WPTR); const float _v=(V); \
  _Pragma("unroll") \
  for (int _o=0;_o<32;_o+=4){ float4 _w4=ld4(_w+_o); \
    A[_o+0]=fmaf(_w4.x,_v,A[_o+0]); A[_o+1]=fmaf(_w4.y,_v,A[_o+1]); \
    A[_o+2]=fmaf(_w4.z,_v,A[_o+2]); A[_o+3]=fmaf(_w4.w,_v,A[_o+3]); } } while(0)

__device__ __forceinline__ void plane_enc(const float* __restrict__ planes,
                                          float p0, float p1, float p2, float* pfv)
{
#pragma unroll
    for (int i=0;i<3;i++){
        float ua = (i==2? p1 : p0)*511.f;
        float va = (i==0? p1 : p2)*511.f;
        float uf=floorf(ua), vf=floorf(va);
        float wu=ua-uf, wv=va-vf;
        int u0=(int)uf; u0 = u0<0?0:(u0>510?510:u0);
        int v0=(int)vf; v0 = v0<0?0:(v0>510?510:v0);
        const float* pl = planes + ((size_t)i*PRES*PRES + (size_t)(u0*PRES+v0))*PFD;
        float4 a0=ld4(pl),              a1=ld4(pl+4);
        float4 b0=ld4(pl+PFD),          b1=ld4(pl+PFD+4);
        float4 c0=ld4(pl+PRES*PFD),     c1=ld4(pl+PRES*PFD+4);
        float4 d0=ld4(pl+PRES*PFD+PFD), d1=ld4(pl+PRES*PFD+PFD+4);
        float w00=(1.f-wu)*(1.f-wv), w01=(1.f-wu)*wv, w10=wu*(1.f-wv), w11=wu*wv;
        pfv[i*8+0]=a0.x*w00+b0.x*w01+c0.x*w10+d0.x*w11;
        pfv[i*8+1]=a0.y*w00+b0.y*w01+c0.y*w10+d0.y*w11;
        pfv[i*8+2]=a0.z*w00+b0.z*w01+c0.z*w10+d0.z*w11;
        pfv[i*8+3]=a0.w*w00+b0.w*w01+c0.w*w10+d0.w*w11;
        pfv[i*8+4]=a1.x*w00+b1.x*w01+c1.x*w10+d1.x*w11;
        pfv[i*8+5]=a1.y*w00+b1.y*w01+c1.y*w10+d1.y*w11;
        pfv[i*8+6]=a1.z*w00+b1.z*w01+c1.z*w10+d1.z*w11;
        pfv[i*8+7]=a1.w*w00+b1.w*w01+c1.w*w10+d1.w*w11;
    }
}

// ===================== K1: hash + plane encode + sigma MLP =====================
// launch_bounds(256,4): 128-VGPR budget; peak live ~100 (acc[64]+gather temps) -> no spill.
// LDS 18.4KB; occupancy VGPR-limited at 16 waves/CU (50%).
__global__ __launch_bounds__(256, 4)
void nerf_k1(const float* __restrict__ x,
             const float* __restrict__ hash_tables,
             const float* __restrict__ planes,
             const float* __restrict__ w_sigma0,
             const float* __restrict__ w_sigma1,
             float* __restrict__ ws16,
             ResArr res, int npts)
{
    __shared__ float s_ws0T[56*64];   // sigma0: in 56 -> out 64 (transposed)
    __shared__ float s_ws1T[64*16];   // sigma1: in 64 -> out 16 (transposed)

    for (int i = threadIdx.x; i < 56*64;  i += 256){ int k=i>>6, o=i&63; s_ws0T[i] = w_sigma0[o*56+k]; }
    for (int i = threadIdx.x; i < 64*16;  i += 256){ int k=i>>4, j=i&15; s_ws1T[i] = w_sigma1[j*64+k]; }
    __syncthreads();

    int n = blockIdx.x*256 + threadIdx.x;
    if (n >= npts) return;

    const float* xr = x + (size_t)n*7;
    float px=xr[0], py=xr[1], pz=xr[2];
    float p0=(px+1.f)*0.5f, p1=(py+1.f)*0.5f, p2=(pz+1.f)*0.5f;

    float acc[HID];
#pragma unroll
    for (int o=0;o<HID;o++) acc[o]=0.f;

    const float2* tabs = reinterpret_cast<const float2*>(hash_tables);
#pragma unroll 2
    for (int l=0; l<NLEV; l++){
        float R = res.v[l];
        float ax=p0*R, ay=p1*R, az=p2*R;
        float fx=floorf(ax), fy=floorf(ay), fz=floorf(az);
        float rx=ax-fx, ry=ay-fy, rz=az-fz;
        uint32_t ix=(uint32_t)fx, iy=(uint32_t)fy, iz=(uint32_t)fz;
        const float2* tab = tabs + (size_t)l*TSIZE;
        uint32_t hx0=ix,               hx1=ix+1u;
        uint32_t hy0=iy*2654435761u,   hy1=(iy+1u)*2654435761u;
        uint32_t hz0=iz*805459861u,    hz1=(iz+1u)*805459861u;
        float wx0=1.f-rx, wx1=rx, wy0=1.f-ry, wy1=ry, wz0=1.f-rz, wz1=rz;
        float f0=0.f, f1=0.f;
#pragma unroll
        for (int c=0;c<8;c++){
            uint32_t hxx=(c&4)?hx1:hx0;
            uint32_t hyy=(c&2)?hy1:hy0;
            uint32_t hzz=(c&1)?hz1:hz0;
            uint32_t idx=(hxx^hyy^hzz)&(TSIZE-1u);
            float2 t = tab[idx];
            float w = ((c&4)?wx1:wx0)*((c&2)?wy1:wy0)*((c&1)?wz1:wz0);
            f0 = fmaf(w,t.x,f0);
            f1 = fmaf(w,t.y,f1);
        }
        AXPY64(acc, &s_ws0T[(2*l+0)*64], f0);
        AXPY64(acc, &s_ws0T[(2*l+1)*64], f1);
    }

    float pfv[24];
    plane_enc(planes, p0, p1, p2, pfv);
#pragma unroll
    for (int j=0;j<24;j++){
        AXPY64(acc, &s_ws0T[(32+j)*64], pfv[j]);
    }

    // sigma1: 16 outputs from relu(acc)
    float h1[16];
#pragma unroll
    for (int j=0;j<16;j++) h1[j]=0.f;
#pragma unroll
    for (int k=0;k<HID;k++){
        float v = fmaxf(acc[k], 0.f);
        const float* wr = &s_ws1T[k*16];
#pragma unroll
        for (int j=0;j<16;j+=4){
            float4 w=ld4(wr+j);
            h1[j+0]=fmaf(w.x,v,h1[j+0]); h1[j+1]=fmaf(w.y,v,h1[j+1]);
            h1[j+2]=fmaf(w.z,v,h1[j+2]); h1[j+3]=fmaf(w.w,v,h1[j+3]);
        }
    }
    float sg = fminf(fmaxf(h1[0], -15.f), 15.f);
    float sigma = expf(sg);

    // ws layout per point: [geo(15), sigma(1)]
    float* w = ws16 + (size_t)n*16;
    *reinterpret_cast<float4*>(w+0)  = make_float4(h1[1],h1[2],h1[3],h1[4]);
    *reinterpret_cast<float4*>(w+4)  = make_float4(h1[5],h1[6],h1[7],h1[8]);
    *reinterpret_cast<float4*>(w+8)  = make_float4(h1[9],h1[10],h1[11],h1[12]);
    *reinterpret_cast<float4*>(w+12) = make_float4(h1[13],h1[14],h1[15],sigma);
}

// ===================== K2: SH + color MLP =====================
// launch_bounds(256,4): 128-VGPR budget. color1 split into 2x32-output passes so
// peak live regs ~106 (acc[64]+acc2h[32]+temps). LDS 43.8KB -> 3 blocks/CU (37.5%).
__global__ __launch_bounds__(256, 4)
void nerf_k2(const float* __restrict__ x,
             const float* __restrict__ planes,
             const float* __restrict__ embed_a,
             const float* __restrict__ w_color0,
             const float* __restrict__ w_color1,
             const float* __restrict__ w_color2,
             const float* __restrict__ ws16,
             float* __restrict__ out, int npts)
{
    __shared__ float s_wc0T[103*64];  // color0: in 103 -> out 64
    __shared__ float s_wc1T[64*64];   // color1: in 64 -> out 64
    __shared__ float s_wc2T[64*4];    // color2: in 64 -> out 3 (pad 4)

    for (int i = threadIdx.x; i < 103*64; i += 256){ int k=i>>6, o=i&63; s_wc0T[i] = w_color0[o*103+k]; }
    for (int i = threadIdx.x; i < 64*64;  i += 256){ int k=i>>6, o=i&63; s_wc1T[i] = w_color1[o*64+k]; }
    for (int i = threadIdx.x; i < 64*4;   i += 256){ int k=i>>2, o=i&3;  s_wc2T[i] = (o<3)? w_color2[o*64+k] : 0.f; }
    __syncthreads();

    int n = blockIdx.x*256 + threadIdx.x;
    if (n >= npts) return;

    const float* xr = x + (size_t)n*7;
    float dx=xr[3], dy=xr[4], dz=xr[5];
    float appf = xr[6];
    float p0=(xr[0]+1.f)*0.5f, p1=(xr[1]+1.f)*0.5f, p2=(xr[2]+1.f)*0.5f;

    float acc[HID];
#pragma unroll
    for (int o=0;o<HID;o++) acc[o]=0.f;

    // SH(16)
    {
        float nrm = sqrtf(dx*dx+dy*dy+dz*dz);
        float sx=dx/nrm, sy=dy/nrm, sz=dz/nrm;
        float xx=sx*sx, yy=sy*sy, zz=sz*sz, xyv=sx*sy, yzv=sy*sz, xzv=sx*sz;
        float sh[16];
        sh[0]=0.28209479177387814f;
        sh[1]=-0.48860251190291987f*sy;
        sh[2]= 0.48860251190291987f*sz;
        sh[3]=-0.48860251190291987f*sx;
        sh[4]= 1.0925484305920792f*xyv;
        sh[5]=-1.0925484305920792f*yzv;
        sh[6]= 0.94617469575756f*zz-0.31539156525252005f;
        sh[7]=-1.0925484305920792f*xzv;
        sh[8]= 0.5462742152960396f*(xx-yy);
        sh[9]=-0.5900435899266435f*sy*(3.f*xx-yy);
        sh[10]=2.890611442640554f*xyv*sz;
        sh[11]=-0.4570457994644658f*sy*(4.f*zz-xx-yy);
        sh[12]=0.3731763325901154f*sz*(2.f*zz-3.f*xx-3.f*yy);
        sh[13]=-0.4570457994644658f*sx*(4.f*zz-xx-yy);
        sh[14]=1.445305721320277f*sz*(xx-yy);
        sh[15]=-0.5900435899266435f*sx*(xx-3.f*yy);
#pragma unroll
        for (int k=0;k<16;k++){
            AXPY64(acc, &s_wc0T[k*64], sh[k]);
        }
    }

    // geo(15) + sigma from workspace
    float sigma;
    {
        const float* wsr = ws16 + (size_t)n*16;
        float4 g0=ld4(wsr), g1=ld4(wsr+4), g2=ld4(wsr+8), g3=ld4(wsr+12);
        float geo[15] = {g0.x,g0.y,g0.z,g0.w, g1.x,g1.y,g1.z,g1.w,
                         g2.x,g2.y,g2.z,g2.w, g3.x,g3.y,g3.z};
        sigma = g3.w;
#pragma unroll
        for (int j=0;j<15;j++){
            AXPY64(acc, &s_wc0T[(16+j)*64], geo[j]);
        }
    }

    // app(48)
    {
        int ai = (int)appf;
        const float* ar = embed_a + (size_t)ai*48;
        for (int q=0;q<12;q++){
            float4 av = ld4(ar + q*4);
            const float* wc = &s_wc0T[(31+q*4)*64];
            AXPY64(acc, wc,       av.x);
            AXPY64(acc, wc+64,    av.y);
            AXPY64(acc, wc+128,   av.z);
            AXPY64(acc, wc+192,   av.w);
        }
    }

    // pf(24), recomputed (cheap, avoids storing 24 floats/pt)
    {
        float pfv[24];
        plane_enc(planes, p0, p1, p2, pfv);
#pragma unroll
        for (int j=0;j<24;j++){
            AXPY64(acc, &s_wc0T[(79+j)*64], pfv[j]);
        }
    }

    // relu color0 output in place
#pragma unroll
    for (int k=0;k<HID;k++) acc[k] = fmaxf(acc[k], 0.f);

    // color1 + color2, split into two 32-output passes to cap live registers.
    float c0a=0.f, c1a=0.f, c2a=0.f;
    {
        float acc2h[32];
#pragma unroll
        for (int o=0;o<32;o++) acc2h[o]=0.f;
#pragma unroll
        for (int k=0;k<HID;k++){
            AXPY32(acc2h, &s_wc1T[k*64], acc[k]);
        }
#pragma unroll
        for (int o=0;o<32;o++){
            float v = fmaxf(acc2h[o], 0.f);
            float4 w = ld4(&s_wc2T[o*4]);
            c0a=fmaf(w.x,v,c0a); c1a=fmaf(w.y,v,c1a); c2a=fmaf(w.z,v,c2a);
        }
    }
    {
        float acc2h[32];
#pragma unroll
        for (int o=0;o<32;o++) acc2h[o]=0.f;
#pragma unroll
        for (int k=0;k<HID;k++){
            AXPY32(acc2h, &s_wc1T[k*64+32], acc[k]);
        }
#pragma unroll
        for (int o=0;o<32;o++){
            float v = fmaxf(acc2h[o], 0.f);
            float4 w = ld4(&s_wc2T[(32+o)*4]);
            c0a=fmaf(w.x,v,c0a); c1a=fmaf(w.y,v,c1a); c2a=fmaf(w.z,v,c2a);
        }
    }

    float4 o4;
    o4.x = 1.f/(1.f+expf(-c0a));
    o4.y = 1.f/(1.f+expf(-c1a));
    o4.z = 1.f/(1.f+expf(-c2a));
    o4.w = sigma;
    *reinterpret_cast<float4*>(out + (size_t)n*4) = o4;
}

// ===================== fallback single kernel (used only if ws too small) =====================
__global__ __launch_bounds__(256, 2)
void nerf_fwd(const float* __restrict__ x,
              const float* __restrict__ hash_tables,
              const float* __restrict__ planes,
              const float* __restrict__ embed_a,
              const float* __restrict__ w_sigma0,
              const float* __restrict__ w_sigma1,
              const float* __restrict__ w_color0,
              const float* __restrict__ w_color1,
              const float* __restrict__ w_color2,
              float* __restrict__ out,
              ResArr res, int npts)
{
    __shared__ float s_ws0T[56*64];
    __shared__ float s_ws1T[64*16];
    __shared__ float s_wc0T[103*64];
    __shared__ float s_wc1T[64*64];
    __shared__ float s_wc2T[64*4];

    for (int i = threadIdx.x; i < 56*64;  i += 256){ int k=i>>6, o=i&63; s_ws0T[i] = w_sigma0[o*56+k]; }
    for (int i = threadIdx.x; i < 64*16;  i += 256){ int k=i>>4, j=i&15; s_ws1T[i] = w_sigma1[j*64+k]; }
    for (int i = threadIdx.x; i < 103*64; i += 256){ int k=i>>6, o=i&63; s_wc0T[i] = w_color0[o*103+k]; }
    for (int i = threadIdx.x; i < 64*64;  i += 256){ int k=i>>6, o=i&63; s_wc1T[i] = w_color1[o*64+k]; }
    for (int i = threadIdx.x; i < 64*4;   i += 256){ int k=i>>2, o=i&3;  s_wc2T[i] = (o<3)? w_color2[o*64+k] : 0.f; }
    __syncthreads();

    int n = blockIdx.x*256 + threadIdx.x;
    if (n >= npts) return;

    const float* xr = x + (size_t)n*7;
    float px=xr[0], py=xr[1], pz=xr[2];
    float dx=xr[3], dy=xr[4], dz=xr[5];
    float appf = xr[6];
    float p0=(px+1.f)*0.5f, p1=(py+1.f)*0.5f, p2=(pz+1.f)*0.5f;

    float acc[HID];
#pragma unroll
    for (int o=0;o<HID;o++) acc[o]=0.f;

    const float2* tabs = reinterpret_cast<const float2*>(hash_tables);
    for (int l=0; l<NLEV; l++){
        float R = res.v[l];
        float ax=p0*R, ay=p1*R, az=p2*R;
        float fx=floorf(ax), fy=floorf(ay), fz=floorf(az);
        float rx=ax-fx, ry=ay-fy, rz=az-fz;
        uint32_t ix=(uint32_t)fx, iy=(uint32_t)fy, iz=(uint32_t)fz;
        const float2* tab = tabs + (size_t)l*TSIZE;
        uint32_t hx0=ix,               hx1=ix+1u;
        uint32_t hy0=iy*2654435761u,   hy1=(iy+1u)*2654435761u;
        uint32_t hz0=iz*805459861u,    hz1=(iz+1u)*805459861u;
        float wx0=1.f-rx, wx1=rx, wy0=1.f-ry, wy1=ry, wz0=1.f-rz, wz1=rz;
        float f0=0.f, f1=0.f;
#pragma unroll
        for (int c=0;c<8;c++){
            uint32_t hxx=(c&4)?hx1:hx0;
            uint32_t hyy=(c&2)?hy1:hy0;
            uint32_t hzz=(c&1)?hz1:hz0;
            uint32_t idx=(hxx^hyy^hzz)&(TSIZE-1u);
            float2 t = tab[idx];
            float w = ((c&4)?wx1:wx0)*((c&2)?wy1:wy0)*((c&1)?wz1:wz0);
            f0 = fmaf(w,t.x,f0);
            f1 = fmaf(w,t.y,f1);
        }
        AXPY64(acc, &s_ws0T[(2*l+0)*64], f0);
        AXPY64(acc, &s_ws0T[(2*l+1)*64], f1);
    }

    float pfv[24];
    plane_enc(planes, p0, p1, p2, pfv);
#pragma unroll
    for (int j=0;j<24;j++){
        AXPY64(acc, &s_ws0T[(32+j)*64], pfv[j]);
    }

    float h1[16];
#pragma unroll
    for (int j=0;j<16;j++) h1[j]=0.f;
#pragma unroll
    for (int k=0;k<HID;k++){
        float v = fmaxf(acc[k], 0.f);
        const float* wr = &s_ws1T[k*16];
#pragma unroll
        for (int j=0;j<16;j+=4){
            float4 w=ld4(wr+j);
            h1[j+0]=fmaf(w.x,v,h1[j+0]); h1[j+1]=fmaf(w.y,v,h1[j+1]);
            h1[j+2]=fmaf(w.z,v,h1[j+2]); h1[j+3]=fmaf(w.w,v,h1[j+3]);
        }
    }
    float sg = fminf(fmaxf(h1[0], -15.f), 15.f);
    float sigma = expf(sg);

#pragma unroll
    for (int o=0;o<HID;o++) acc[o]=0.f;

    float nrm = sqrtf(dx*dx+dy*dy+dz*dz);
    float sx=dx/nrm, sy=dy/nrm, sz=dz/nrm;
    float xx=sx*sx, yy=sy*sy, zz=sz*sz, xyv=sx*sy, yzv=sy*sz, xzv=sx*sz;
    float sh[16];
    sh[0]=0.28209479177387814f;
    sh[1]=-0.48860251190291987f*sy;
    sh[2]= 0.48860251190291987f*sz;
    sh[3]=-0.48860251190291987f*sx;
    sh[4]= 1.0925484305920792f*xyv;
    sh[5]=-1.0925484305920792f*yzv;
    sh[6]= 0.94617469575756f*zz-0.31539156525252005f;
    sh[7]=-1.0925484305920792f*xzv;
    sh[8]= 0.5462742152960396f*(xx-yy);
    sh[9]=-0.5900435899266435f*sy*(3.f*xx-yy);
    sh[10]=2.890611442640554f*xyv*sz;
    sh[11]=-0.4570457994644658f*sy*(4.f*zz-xx-yy);
    sh[12]=0.3731763325901154f*sz*(2.f*zz-3.f*xx-3.f*yy);
    sh[13]=-0.4570457994644658f*sx*(4.f*zz-xx-yy);
    sh[14]=1.445305721320277f*sz*(xx-yy);
    sh[15]=-0.5900435899266435f*sx*(xx-3.f*yy);
#pragma unroll
    for (int k=0;k<16;k++){
        AXPY64(acc, &s_wc0T[k*64], sh[k]);
    }
#pragma unroll
    for (int j=0;j<15;j++){
        AXPY64(acc, &s_wc0T[(16+j)*64], h1[1+j]);
    }
    {
        int ai = (int)appf;
        const float* ar = embed_a + (size_t)ai*48;
        for (int q=0;q<12;q++){
            float4 av = ld4(ar + q*4);
            const float* wc = &s_wc0T[(31+q*4)*64];
            AXPY64(acc, wc,       av.x);
            AXPY64(acc, wc+64,    av.y);
            AXPY64(acc, wc+128,   av.z);
            AXPY64(acc, wc+192,   av.w);
        }
    }
#pragma unroll
    for (int j=0;j<24;j++){
        AXPY64(acc, &s_wc0T[(79+j)*64], pfv[j]);
    }

    float acc2[HID];
#pragma unroll
    for (int o=0;o<HID;o++) acc2[o]=0.f;
#pragma unroll
    for (int k=0;k<HID;k++){
        float v = fmaxf(acc[k], 0.f);
        AXPY64(acc2, &s_wc1T[k*64], v);
    }

    float c0a=0.f, c1a=0.f, c2a=0.f;
#pragma unroll
    for (int k=0;k<HID;k++){
        float v = fmaxf(acc2[k], 0.f);
        float4 w = ld4(&s_wc2T[k*4]);
        c0a=fmaf(w.x,v,c0a); c1a=fmaf(w.y,v,c1a); c2a=fmaf(w.z,v,c2a);
    }
    float4 o4;
    o4.x = 1.f/(1.f+expf(-c0a));
    o4.y = 1.f/(1.f+expf(-c1a));
    o4.z = 1.f/(1.f+expf(-c2a));
    o4.w = sigma;
    *reinterpret_cast<float4*>(out + (size_t)n*4) = o4;
}

extern "C" void kernel_launch(void* const* d_in, const int* in_sizes, int n_in,
                              void* d_out, int out_size, void* d_ws, size_t ws_size,
                              hipStream_t stream) {
    const float* x        = (const float*)d_in[0];
    const float* ht       = (const float*)d_in[1];
    const float* planes   = (const float*)d_in[2];
    const float* embed_a  = (const float*)d_in[3];
    const float* w_sigma0 = (const float*)d_in[4];
    const float* w_sigma1 = (const float*)d_in[5];
    const float* w_color0 = (const float*)d_in[6];
    const float* w_color1 = (const float*)d_in[7];
    const float* w_color2 = (const float*)d_in[8];
    float* out = (float*)d_out;

    int npts = in_sizes[0] / 7;

    // Replicate numpy's RES bit-exactly (same libm chain).
    ResArr res;
    double b = exp((log(2048.0) - log(16.0)) / 15.0);
    for (int l=0; l<NLEV; l++)
        res.v[l] = (float)floor(16.0 * pow(b, (double)l));

    size_t ws_needed = (size_t)npts * 16 * sizeof(float);
    if (ws_size >= ws_needed) {
        float* ws16 = (float*)d_ws;
        int g1 = (npts + 255) / 256;
        hipLaunchKernelGGL(nerf_k1, dim3(g1), dim3(256), 0, stream,
                           x, ht, planes, w_sigma0, w_sigma1, ws16, res, npts);
        int g2 = (npts + 255) / 256;
        hipLaunchKernelGGL(nerf_k2, dim3(g2), dim3(256), 0, stream,
                           x, planes, embed_a, w_color0, w_color1, w_color2,
                           ws16, out, npts);
    } else {
        int grid = (npts + 255) / 256;
        hipLaunchKernelGGL(nerf_fwd, dim3(grid), dim3(256), 0, stream,
                           x, ht, planes, embed_a,
                           w_sigma0, w_sigma1, w_color0, w_color1, w_color2,
                           out, res, npts);
    }
}